// Round 2
// baseline (1084.743 us; speedup 1.0000x reference)
//
#include <hip/hip_runtime.h>
#include <math.h>

#define N_TOT 4096   // H*P*D
#define PHO_T 4096   // P*H*OUT_DIM
#define KTOT  40960  // 2*N + 8*N

// ---------------------------------------------------------------------------
// Pass 1: activation matrix A[k][b], k-major, b minor (32 floats per k row).
//   k in [0,4096)      : silu(q[b][n]),  n = k
//   k in [4096,8192)   : silu(k[b][n])
//   k in [8192,40960)  : sin(grid_f*q)*ce_q + sin(grid_f*k)*ce_k, f-major
// ---------------------------------------------------------------------------
__global__ void act_kernel(const float* __restrict__ q,
                           const float* __restrict__ kx,
                           const float* __restrict__ grid_,
                           const float* __restrict__ coefq,
                           const float* __restrict__ coefk,
                           float* __restrict__ A)
{
    const int t = blockIdx.x * 256 + threadIdx.x;  // 131072 total = 4096 n * 32 b
    const int b = t & 31;
    const int n = t >> 5;
    const float qv = q[(size_t)b * N_TOT + n];
    const float kv = kx[(size_t)b * N_TOT + n];
    A[(size_t)n * 32 + b]           = qv / (1.f + __expf(-qv));
    A[(size_t)(N_TOT + n) * 32 + b] = kv / (1.f + __expf(-kv));
    const int g = n >> 6;  // group = n/64
#pragma unroll
    for (int f = 0; f < 8; ++f) {
        const float gf = grid_[f];
        const float s = sinf(gf * qv) * coefq[g * 8 + f]
                      + sinf(gf * kv) * coefk[g * 8 + f];
        A[(size_t)(2 * N_TOT + f * N_TOT + n) * 32 + b] = s;
    }
}

// ---------------------------------------------------------------------------
// y_pre[b][o] initialized with the bias term: 2 * ss[o]^2 * sum_f conv_bq[f][o]
// ---------------------------------------------------------------------------
__global__ void init_kernel(const float* __restrict__ cb,
                            const float* __restrict__ ssp,
                            float* __restrict__ ypre)
{
    const int t = blockIdx.x * 256 + threadIdx.x;  // t = b*4096 + o
    const int o = t & 4095;
    const float s = ssp[o];
    float acc = 0.f;
#pragma unroll
    for (int f = 0; f < 8; ++f) acc += cb[f * PHO_T + o];
    ypre[t] = 2.f * s * s * acc;
}

// ---------------------------------------------------------------------------
// Main GEMM: y_pre[b][o] += scale * sum_k A[k][b] * W[k][o]
// Grid: 160 K-supers (256 k, region-aligned) x 16 o-blocks (256 o).
// Block: 256 threads; thread t owns o = o_base + t, all 32 b (acc[32]).
// Chunk = 32 k (128 B per weight row -> full cache-line utilization, zero
// over-fetch). Stage: 8 consecutive lanes cover one row's 128 B (8 fully-
// used 128B segments per wave instruction). LDS [row][9 float4] (pad f4
// keeps ds_read_b128/write_b128 at structural-minimum bank usage),
// double-buffered = 73.7 KB -> 2 blocks/CU, loads prefetched 1 chunk ahead.
// A read with wave-uniform addresses (scalarizes; L2-resident).
// ---------------------------------------------------------------------------
#define OBK  256
#define KC   32
#define KSUP 256
#define NCH  (KSUP / KC)   // 8 chunks per block
#define F4ST 9             // float4 stride per LDS row

__global__ __launch_bounds__(256, 2) void gemm_kernel(
    const float* __restrict__ bwq, const float* __restrict__ bwk,
    const float* __restrict__ cw,  const float* __restrict__ A,
    const float* __restrict__ ssp, float* __restrict__ ypre)
{
    __shared__ float Wl[2][OBK * F4ST * 4];   // 2 * 36864 B = 73728 B

    const int t  = threadIdx.x;
    const int ks = blockIdx.x >> 4;      // 0..159
    const int ob = blockIdx.x & 15;      // 0..15
    const int o_base = ob * OBK;

    const float* Wp;
    int a_koff;
    bool scaled;
    if (ks < 16) {                       // base_weight_q
        Wp = bwq + ks * 256;
        a_koff = ks * 256;
        scaled = false;
    } else if (ks < 32) {                // base_weight_k
        Wp = bwk + (ks - 16) * 256;
        a_koff = 4096 + (ks - 16) * 256;
        scaled = false;
    } else {                             // conv_wq, scaled by ss^2
        const int c2 = ks - 32;          // 0..127
        const int f  = c2 >> 4;          // 0..7
        const int noff = (c2 & 15) * 256;
        Wp = cw + (size_t)f * (size_t)PHO_T * N_TOT + noff;
        a_koff = 8192 + f * 4096 + noff;
        scaled = true;
    }

    const int li = t & 7;   // float4 index within a row's 32-k chunk
    const int rg = t >> 3;  // row group 0..31; rows rg + 32*i

    float acc[32];
#pragma unroll
    for (int i = 0; i < 32; ++i) acc[i] = 0.f;

    float4 wreg[8];

    auto stage_load = [&](int c) {
        const int k0 = c * KC;
#pragma unroll
        for (int i = 0; i < 8; ++i) {
            const int row = rg + 32 * i;
            wreg[i] = *(const float4*)(Wp + (size_t)(o_base + row) * N_TOT + k0 + li * 4);
        }
    };
    auto stage_write = [&](int buf) {
#pragma unroll
        for (int i = 0; i < 8; ++i) {
            const int row = rg + 32 * i;
            *(float4*)&Wl[buf][(row * F4ST + li) * 4] = wreg[i];
        }
    };

    // prologue: stage chunk 0
    stage_load(0);
    stage_write(0);
    __syncthreads();

    for (int c = 0; c < NCH; ++c) {
        const int cur = c & 1;
        if (c + 1 < NCH) stage_load(c + 1);   // in flight over compute

        const float* __restrict__ Ab = A + ((size_t)a_koff + (size_t)c * KC) * 32;
#pragma unroll
        for (int k4 = 0; k4 < 8; ++k4) {
            const float4 w4 = *(const float4*)&Wl[cur][(t * F4ST + k4) * 4];
#pragma unroll
            for (int j = 0; j < 4; ++j) {
                const float wv = (j == 0) ? w4.x : (j == 1) ? w4.y : (j == 2) ? w4.z : w4.w;
                const float4* __restrict__ ap = (const float4*)(Ab + (k4 * 4 + j) * 32);
#pragma unroll
                for (int b4 = 0; b4 < 8; ++b4) {
                    const float4 a = ap[b4];   // wave-uniform -> scalar broadcast
                    acc[b4 * 4 + 0] = fmaf(a.x, wv, acc[b4 * 4 + 0]);
                    acc[b4 * 4 + 1] = fmaf(a.y, wv, acc[b4 * 4 + 1]);
                    acc[b4 * 4 + 2] = fmaf(a.z, wv, acc[b4 * 4 + 2]);
                    acc[b4 * 4 + 3] = fmaf(a.w, wv, acc[b4 * 4 + 3]);
                }
            }
        }

        if (c + 1 < NCH) {
            // safe: last readers of buffer cur^1 finished before the barrier
            // at the end of iteration c-1
            stage_write(cur ^ 1);
            __syncthreads();
        }
    }

    // epilogue: scale (conv blocks get ss^2) and accumulate partials
    const int o0 = o_base + t;
    float s0 = 1.f;
    if (scaled) {
        const float x0 = ssp[o0];
        s0 = x0 * x0;
    }
#pragma unroll
    for (int b = 0; b < 32; ++b) {
        atomicAdd(&ypre[(size_t)b * PHO_T + o0], acc[b] * s0);
    }
}

// ---------------------------------------------------------------------------
// Softmax over the last dim (32) of y.reshape(32,8,16,32): rows of 32
// contiguous elements. One 32-lane group per row.
// ---------------------------------------------------------------------------
__global__ void softmax_kernel(const float* __restrict__ yp,
                               float* __restrict__ out)
{
    const int t  = threadIdx.x;
    const int r  = blockIdx.x * 8 + (t >> 5);  // 4096 rows
    const int od = t & 31;
    const float v = yp[(size_t)r * 32 + od];
    float m = v;
#pragma unroll
    for (int s = 16; s > 0; s >>= 1) m = fmaxf(m, __shfl_xor(m, s, 32));
    const float e = __expf(v - m);
    float sum = e;
#pragma unroll
    for (int s = 16; s > 0; s >>= 1) sum += __shfl_xor(sum, s, 32);
    out[(size_t)r * 32 + od] = e / sum;
}

// ---------------------------------------------------------------------------
extern "C" void kernel_launch(void* const* d_in, const int* in_sizes, int n_in,
                              void* d_out, int out_size, void* d_ws, size_t ws_size,
                              hipStream_t stream)
{
    const float* q    = (const float*)d_in[0];
    const float* k    = (const float*)d_in[1];
    const float* grid = (const float*)d_in[2];
    const float* bwq  = (const float*)d_in[3];
    const float* bwk  = (const float*)d_in[4];
    const float* cq   = (const float*)d_in[5];
    const float* ck   = (const float*)d_in[6];
    const float* cw   = (const float*)d_in[7];
    const float* cb   = (const float*)d_in[8];
    const float* ssp  = (const float*)d_in[9];
    float* out = (float*)d_out;

    float* A    = (float*)d_ws;                                  // 40960*32*4 = 5242880 B
    float* ypre = (float*)((char*)d_ws + (size_t)KTOT * 32 * 4); // 131072*4   =  524288 B

    act_kernel<<<512, 256, 0, stream>>>(q, k, grid, cq, ck, A);
    init_kernel<<<512, 256, 0, stream>>>(cb, ssp, ypre);
    gemm_kernel<<<2560, 256, 0, stream>>>(bwq, bwk, cw, A, ssp, ypre);
    softmax_kernel<<<512, 256, 0, stream>>>(ypre, out);
}

// Round 3
// 357.822 us; speedup vs baseline: 3.0315x; 3.0315x over previous
//
#include <hip/hip_runtime.h>
#include <math.h>

#define N_TOT 4096   // H*P*D
#define PHO_T 4096   // P*H*OUT_DIM
#define KTOT  40960  // 2*N + 8*N

// global -> LDS direct DMA, 16 B per lane, dest = uniform base + lane*16
#define GLD16(src, dst) __builtin_amdgcn_global_load_lds(                      \
    (const __attribute__((address_space(1))) void*)(src),                      \
    (__attribute__((address_space(3))) void*)(dst), 16, 0, 0)

// ---------------------------------------------------------------------------
// Pass 1: activation matrix A[k][b], k-major, b minor (32 floats per k row).
//   k in [0,4096)      : silu(q[b][n]),  n = k
//   k in [4096,8192)   : silu(k[b][n])
//   k in [8192,40960)  : sin(grid_f*q)*ce_q + sin(grid_f*k)*ce_k, f-major
// ---------------------------------------------------------------------------
__global__ void act_kernel(const float* __restrict__ q,
                           const float* __restrict__ kx,
                           const float* __restrict__ grid_,
                           const float* __restrict__ coefq,
                           const float* __restrict__ coefk,
                           float* __restrict__ A)
{
    const int t = blockIdx.x * 256 + threadIdx.x;  // 131072 total = 4096 n * 32 b
    const int b = t & 31;
    const int n = t >> 5;
    const float qv = q[(size_t)b * N_TOT + n];
    const float kv = kx[(size_t)b * N_TOT + n];
    A[(size_t)n * 32 + b]           = qv / (1.f + __expf(-qv));
    A[(size_t)(N_TOT + n) * 32 + b] = kv / (1.f + __expf(-kv));
    const int g = n >> 6;  // group = n/64
#pragma unroll
    for (int f = 0; f < 8; ++f) {
        const float gf = grid_[f];
        const float s = sinf(gf * qv) * coefq[g * 8 + f]
                      + sinf(gf * kv) * coefk[g * 8 + f];
        A[(size_t)(2 * N_TOT + f * N_TOT + n) * 32 + b] = s;
    }
}

// ---------------------------------------------------------------------------
// y_pre[b][o] initialized with the bias term: 2 * ss[o]^2 * sum_f conv_bq[f][o]
// ---------------------------------------------------------------------------
__global__ void init_kernel(const float* __restrict__ cb,
                            const float* __restrict__ ssp,
                            float* __restrict__ ypre)
{
    const int t = blockIdx.x * 256 + threadIdx.x;  // t = b*4096 + o
    const int o = t & 4095;
    const float s = ssp[o];
    float acc = 0.f;
#pragma unroll
    for (int f = 0; f < 8; ++f) acc += cb[f * PHO_T + o];
    ypre[t] = 2.f * s * s * acc;
}

// ---------------------------------------------------------------------------
// Main GEMM: y_pre[b][o] += scale * sum_k A[k][b] * W[k][o]
// Grid: 160 K-supers (256 k, region-aligned) x 16 o-blocks (256 o).
// Block: 256 threads; thread t owns o = o_base + t, all 32 b (acc[32]).
// Chunk = 32 k (128 B per weight row). Staging via global_load_lds (16 B/lane,
// zero VGPRs -> no spill), double-buffered 2x32 KB. LDS is row-major [256][32]
// f32 with an XOR slot swizzle applied on BOTH sides (rule #21):
//   LDS (row, s) holds global (row, s ^ (row&7))
// DMA source: each 8-lane group reads one aligned 128-B row segment (permuted
// within the line -> still one coalesced request). Read: slot k4 ^ (t&7) ->
// conflict-free ds_read_b128. A read with wave-uniform addresses (scalarized).
// ---------------------------------------------------------------------------
#define OBK  256
#define KC   32
#define KSUP 256
#define NCH  (KSUP / KC)   // 8 chunks per block

__global__ __launch_bounds__(256) void gemm_kernel(
    const float* __restrict__ bwq, const float* __restrict__ bwk,
    const float* __restrict__ cw,  const float* __restrict__ A,
    const float* __restrict__ ssp, float* __restrict__ ypre)
{
    __shared__ float Wl[2][OBK * KC];   // 2 * 32768 B = 65536 B

    const int t  = threadIdx.x;
    const int ks = blockIdx.x >> 4;      // 0..159
    const int ob = blockIdx.x & 15;      // 0..15
    const int o_base = ob * OBK;

    const float* Wp;
    int a_koff;
    bool scaled;
    if (ks < 16) {                       // base_weight_q
        Wp = bwq + ks * 256;
        a_koff = ks * 256;
        scaled = false;
    } else if (ks < 32) {                // base_weight_k
        Wp = bwk + (ks - 16) * 256;
        a_koff = 4096 + (ks - 16) * 256;
        scaled = false;
    } else {                             // conv_wq, scaled by ss^2
        const int c2 = ks - 32;          // 0..127
        const int f  = c2 >> 4;          // 0..7
        const int noff = (c2 & 15) * 256;
        Wp = cw + (size_t)f * (size_t)PHO_T * N_TOT + noff;
        a_koff = 8192 + f * 4096 + noff;
        scaled = true;
    }

    const int wv = t >> 6;   // wave 0..3
    const int ln = t & 63;   // lane
    // DMA source swizzle: lane ln covers (row = ln>>3, slot = (ln&7)^((ln>>3)&7))
    const int srow = ln >> 3;
    const int sslot = (ln & 7) ^ (srow & 7);

    float acc[32];
#pragma unroll
    for (int i = 0; i < 32; ++i) acc[i] = 0.f;

    // stage chunk c into buffer buf: 8 DMA instructions per wave, each moving
    // 8 rows x 128 B (1024 B contiguous LDS)
    auto stage = [&](int c, int buf) {
        const int k0 = c * KC;
#pragma unroll
        for (int i = 0; i < 8; ++i) {
            const int row = wv * 64 + i * 8 + srow;
            const float* src = Wp + (size_t)(o_base + row) * N_TOT + k0 + sslot * 4;
            GLD16(src, &Wl[buf][(wv * 64 + i * 8) * KC]);
        }
    };

    // prologue
    stage(0, 0);
    __syncthreads();   // vmcnt(0) drain + barrier: chunk 0 resident

    const int sw = t & 7;   // read-side swizzle key

    for (int c = 0; c < NCH; ++c) {
        const int cur = c & 1;
        if (c + 1 < NCH) stage(c + 1, cur ^ 1);   // DMA in flight over compute

        const float* __restrict__ wl_row = &Wl[cur][t * KC];
        const float* __restrict__ Ab = A + ((size_t)a_koff + (size_t)c * KC) * 32;
#pragma unroll
        for (int k4 = 0; k4 < 8; ++k4) {
            const float4 w4 = *(const float4*)&wl_row[(k4 ^ sw) * 4];
#pragma unroll
            for (int j = 0; j < 4; ++j) {
                const float wv4 = (j == 0) ? w4.x : (j == 1) ? w4.y : (j == 2) ? w4.z : w4.w;
                const float4* __restrict__ ap = (const float4*)(Ab + (k4 * 4 + j) * 32);
#pragma unroll
                for (int b4 = 0; b4 < 8; ++b4) {
                    const float4 a = ap[b4];   // wave-uniform -> scalar broadcast
                    acc[b4 * 4 + 0] = fmaf(a.x, wv4, acc[b4 * 4 + 0]);
                    acc[b4 * 4 + 1] = fmaf(a.y, wv4, acc[b4 * 4 + 1]);
                    acc[b4 * 4 + 2] = fmaf(a.z, wv4, acc[b4 * 4 + 2]);
                    acc[b4 * 4 + 3] = fmaf(a.w, wv4, acc[b4 * 4 + 3]);
                }
            }
        }
        // barrier: (a) compiler-inserted vmcnt(0) drains the DMA for cur^1,
        // (b) all waves done reading cur before next iteration's DMA overwrites it
        __syncthreads();
    }

    // epilogue: scale (conv blocks get ss^2) and accumulate partials
    const int o0 = o_base + t;
    float s0 = 1.f;
    if (scaled) {
        const float x0 = ssp[o0];
        s0 = x0 * x0;
    }
#pragma unroll
    for (int b = 0; b < 32; ++b) {
        atomicAdd(&ypre[(size_t)b * PHO_T + o0], acc[b] * s0);
    }
}

// ---------------------------------------------------------------------------
// Softmax over the last dim (32) of y.reshape(32,8,16,32): rows of 32
// contiguous elements. One 32-lane group per row.
// ---------------------------------------------------------------------------
__global__ void softmax_kernel(const float* __restrict__ yp,
                               float* __restrict__ out)
{
    const int t  = threadIdx.x;
    const int r  = blockIdx.x * 8 + (t >> 5);  // 4096 rows
    const int od = t & 31;
    const float v = yp[(size_t)r * 32 + od];
    float m = v;
#pragma unroll
    for (int s = 16; s > 0; s >>= 1) m = fmaxf(m, __shfl_xor(m, s, 32));
    const float e = __expf(v - m);
    float sum = e;
#pragma unroll
    for (int s = 16; s > 0; s >>= 1) sum += __shfl_xor(sum, s, 32);
    out[(size_t)r * 32 + od] = e / sum;
}

// ---------------------------------------------------------------------------
extern "C" void kernel_launch(void* const* d_in, const int* in_sizes, int n_in,
                              void* d_out, int out_size, void* d_ws, size_t ws_size,
                              hipStream_t stream)
{
    const float* q    = (const float*)d_in[0];
    const float* k    = (const float*)d_in[1];
    const float* grid = (const float*)d_in[2];
    const float* bwq  = (const float*)d_in[3];
    const float* bwk  = (const float*)d_in[4];
    const float* cq   = (const float*)d_in[5];
    const float* ck   = (const float*)d_in[6];
    const float* cw   = (const float*)d_in[7];
    const float* cb   = (const float*)d_in[8];
    const float* ssp  = (const float*)d_in[9];
    float* out = (float*)d_out;

    float* A    = (float*)d_ws;                                  // 40960*32*4 = 5242880 B
    float* ypre = (float*)((char*)d_ws + (size_t)KTOT * 32 * 4); // 131072*4   =  524288 B

    act_kernel<<<512, 256, 0, stream>>>(q, k, grid, cq, ck, A);
    init_kernel<<<512, 256, 0, stream>>>(cb, ssp, ypre);
    gemm_kernel<<<2560, 256, 0, stream>>>(bwq, bwk, cw, A, ssp, ypre);
    softmax_kernel<<<512, 256, 0, stream>>>(ypre, out);
}

// Round 4
// 168.929 us; speedup vs baseline: 6.4213x; 2.1182x over previous
//
#include <hip/hip_runtime.h>
#include <math.h>

#define N_TOT 4096   // H*P*D
#define PHO_T 4096   // P*H*OUT_DIM
#define KTOT  40960  // 2*N + 8*N
#define NS    2560   // total k16 steps = KTOT/16

typedef __attribute__((ext_vector_type(8)))  short short8v;  // 8 bf16 (4 VGPRs)
typedef __attribute__((ext_vector_type(16))) float f32x16;   // MFMA 32x32 acc

// global -> LDS direct DMA, 16 B per lane, dest = wave-uniform base + lane*16
#define GLD16(src, dst) __builtin_amdgcn_global_load_lds(                      \
    (const __attribute__((address_space(1))) void*)(src),                      \
    (__attribute__((address_space(3))) void*)(dst), 16, 0, 0)

// f32 -> (hi,lo) bf16, RNE on both (residual exact; dropped lo*lo term is
// zero-mean => no systematic bias in the GEMM)
__device__ __forceinline__ void split1(float x, short& h, short& l) {
    unsigned u  = __builtin_bit_cast(unsigned, x);
    unsigned hu = (u + 0x7FFFu + ((u >> 16) & 1u)) & 0xFFFF0000u;
    h = (short)(hu >> 16);
    float r = x - __builtin_bit_cast(float, hu);     // exact
    unsigned ur = __builtin_bit_cast(unsigned, r);
    l = (short)((ur + 0x7FFFu + ((ur >> 16) & 1u)) >> 16);
}

// ---------------------------------------------------------------------------
// Pass 1: A in MFMA-fragment order, hi/lo bf16 planes.
//   logical Act[k][b]: k<4096 silu(q), k<8192 silu(k), else sin-features.
//   fragment stream: for k16-step S, plane p, lane l:
//     Af[((S*2+p)*64 + l)*8 + j] = Act_p[b = l&31][k = S*16 + (l>>5)*8 + j]
//   (exactly the 32x32x16 bf16 A-operand layout; 1 KB per (S,p), coalesced)
// ---------------------------------------------------------------------------
__global__ void act_kernel(const float* __restrict__ q,
                           const float* __restrict__ kx,
                           const float* __restrict__ grid_,
                           const float* __restrict__ coefq,
                           const float* __restrict__ coefk,
                           short* __restrict__ Af)
{
    const int t = blockIdx.x * 256 + threadIdx.x;  // 163840 = NS * 64
    const int S = t >> 6;
    const int l = t & 63;
    const int b = l & 31;
    const int k0 = S * 16 + (l >> 5) * 8;          // 8-aligned; never crosses a region

    float v[8];
    if (k0 < 8192) {
        const float* src = (k0 < 4096) ? (q  + (size_t)b * N_TOT + k0)
                                       : (kx + (size_t)b * N_TOT + (k0 - 4096));
#pragma unroll
        for (int j = 0; j < 8; ++j) {
            const float x = src[j];
            v[j] = x / (1.f + __expf(-x));
        }
    } else {
        const int f  = (k0 - 8192) >> 12;
        const int n0 = (k0 - 8192) & 4095;         // 8-aligned -> same group for all j
        const int g  = n0 >> 6;
        const float gf  = grid_[f];
        const float cq_ = coefq[g * 8 + f];
        const float ck_ = coefk[g * 8 + f];
        const float* qp = q  + (size_t)b * N_TOT + n0;
        const float* kp = kx + (size_t)b * N_TOT + n0;
#pragma unroll
        for (int j = 0; j < 8; ++j)
            v[j] = sinf(gf * qp[j]) * cq_ + sinf(gf * kp[j]) * ck_;
    }

    short8v hi, lo;
#pragma unroll
    for (int j = 0; j < 8; ++j) { short h, lw; split1(v[j], h, lw); hi[j] = h; lo[j] = lw; }
    *(short8v*)&Af[((size_t)(S * 2 + 0) * 64 + l) * 8] = hi;
    *(short8v*)&Af[((size_t)(S * 2 + 1) * 64 + l) * 8] = lo;
}

// ---------------------------------------------------------------------------
// y_pre[b][o] initialized with the bias term: 2 * ss[o]^2 * sum_f conv_bq[f][o]
// ---------------------------------------------------------------------------
__global__ void init_kernel(const float* __restrict__ cb,
                            const float* __restrict__ ssp,
                            float* __restrict__ ypre)
{
    const int t = blockIdx.x * 256 + threadIdx.x;  // t = b*4096 + o
    const int o = t & 4095;
    const float s = ssp[o];
    float acc = 0.f;
#pragma unroll
    for (int f = 0; f < 8; ++f) acc += cb[f * PHO_T + o];
    ypre[t] = 2.f * s * s * acc;
}

// ---------------------------------------------------------------------------
// Main GEMM via split-bf16 MFMA: y[b][o] += sum_k Act[k][b] * W[k][o]
//   ~ ah*wh + ah*wl + al*wh  (3x mfma_f32_32x32x16_bf16)
// Grid: 160 K-supers (256 k) x 16 o-blocks (256 o). Block 256 = 4 waves;
// wave w owns o in [o_base + w*64, +64): two 32-wide N-tiles. All 32 b per
// tile in one MFMA chain (acc f32x16 per tile).
// W f32 staged by global_load_lds (r3 path, XOR slot swizzle both sides),
// converted to bf16 hi/lo in-register (once per element machine-wide).
// A read as ready-made fragments (coalesced b128, L2/L3-resident).
// ---------------------------------------------------------------------------
#define OBK  256
#define KC   32
#define NCH  8      // 256 k per block / KC

__global__ __launch_bounds__(256) void gemm_kernel(
    const float* __restrict__ bwq, const float* __restrict__ bwk,
    const float* __restrict__ cw,  const short* __restrict__ Af,
    const float* __restrict__ ssp, float* __restrict__ ypre)
{
    __shared__ float Wl[2][OBK * KC];   // 2 * 32 KB

    const int t  = threadIdx.x;
    const int ks = blockIdx.x >> 4;      // 0..159
    const int ob = blockIdx.x & 15;      // 0..15
    const int o_base = ob * OBK;

    const float* Wp;
    int s_base;          // k16-step base into Af
    bool scaled;
    if (ks < 16) {                       // base_weight_q
        Wp = bwq + ks * 256;
        s_base = ks * 16;
        scaled = false;
    } else if (ks < 32) {                // base_weight_k
        Wp = bwk + (ks - 16) * 256;
        s_base = 256 + (ks - 16) * 16;
        scaled = false;
    } else {                             // conv_wq, scaled by ss^2
        const int c2 = ks - 32;          // 0..127
        const int f  = c2 >> 4;          // 0..7
        const int noff = (c2 & 15) * 256;
        Wp = cw + (size_t)f * (size_t)PHO_T * N_TOT + noff;
        s_base = 512 + f * 256 + (c2 & 15) * 16;
        scaled = true;
    }

    const int w  = t >> 6;   // wave 0..3
    const int l  = t & 63;   // lane
    const int srow  = l >> 3;
    const int sslot = (l & 7) ^ (srow & 7);   // DMA source swizzle (rule #21)

    f32x16 acc0, acc1;
#pragma unroll
    for (int i = 0; i < 16; ++i) { acc0[i] = 0.f; acc1[i] = 0.f; }

    auto stage = [&](int c, int buf) {
        const int k0 = c * KC;
#pragma unroll
        for (int i = 0; i < 8; ++i) {
            const int row = w * 64 + i * 8 + srow;
            const float* src = Wp + (size_t)(o_base + row) * N_TOT + k0 + sslot * 4;
            GLD16(src, &Wl[buf][(w * 64 + i * 8) * KC]);
        }
    };

    stage(0, 0);
    __syncthreads();   // vmcnt(0) drain + barrier: chunk 0 resident

    const int rkey = l & 7;              // row&7 for both tiles (nt*32 = 0 mod 8)
    const int row0 = w * 64 + (l & 31);

    for (int c = 0; c < NCH; ++c) {
        const int cur = c & 1;
        if (c + 1 < NCH) stage(c + 1, cur ^ 1);   // DMA in flight over compute

#pragma unroll
        for (int s = 0; s < 2; ++s) {
            const size_t Sg = (size_t)(s_base + c * 2 + s);
            const short8v ah = *(const short8v*)&Af[((Sg * 2 + 0) * 64 + l) * 8];
            const short8v al = *(const short8v*)&Af[((Sg * 2 + 1) * 64 + l) * 8];
            const int j0 = s * 4 + (l >> 5) * 2;   // logical f4 slot of this lane's 8 k

            auto tileop = [&](int nt, f32x16& acc) {
                const float* rp = &Wl[cur][(row0 + nt * 32) * KC];
                const float4 wa = *(const float4*)&rp[((j0    ) ^ rkey) * 4];
                const float4 wb = *(const float4*)&rp[((j0 + 1) ^ rkey) * 4];
                short8v bh, bl;
                {
                    short h, lw;
                    split1(wa.x, h, lw); bh[0] = h; bl[0] = lw;
                    split1(wa.y, h, lw); bh[1] = h; bl[1] = lw;
                    split1(wa.z, h, lw); bh[2] = h; bl[2] = lw;
                    split1(wa.w, h, lw); bh[3] = h; bl[3] = lw;
                    split1(wb.x, h, lw); bh[4] = h; bl[4] = lw;
                    split1(wb.y, h, lw); bh[5] = h; bl[5] = lw;
                    split1(wb.z, h, lw); bh[6] = h; bl[6] = lw;
                    split1(wb.w, h, lw); bh[7] = h; bl[7] = lw;
                }
                acc = __builtin_amdgcn_mfma_f32_32x32x16_bf16(ah, bh, acc, 0, 0, 0);
                acc = __builtin_amdgcn_mfma_f32_32x32x16_bf16(ah, bl, acc, 0, 0, 0);
                acc = __builtin_amdgcn_mfma_f32_32x32x16_bf16(al, bh, acc, 0, 0, 0);
            };
            tileop(0, acc0);
            tileop(1, acc1);
        }
        // barrier: compiler-inserted vmcnt(0) drains next chunk's DMA; also
        // protects buffer `cur` from the following iteration's overwrite
        __syncthreads();
    }

    // epilogue: D layout (32x32): col = l&31, row(b) = (r&3) + 8*(r>>2) + 4*(l>>5)
    const int o0 = o_base + w * 64 + (l & 31);
    const int o1 = o0 + 32;
    float s0 = 1.f, s1 = 1.f;
    if (scaled) {
        const float x0 = ssp[o0], x1 = ssp[o1];
        s0 = x0 * x0; s1 = x1 * x1;
    }
    const int bh4 = 4 * (l >> 5);
#pragma unroll
    for (int r = 0; r < 16; ++r) {
        const int b = (r & 3) + 8 * (r >> 2) + bh4;
        atomicAdd(&ypre[(size_t)b * PHO_T + o0], acc0[r] * s0);
        atomicAdd(&ypre[(size_t)b * PHO_T + o1], acc1[r] * s1);
    }
}

// ---------------------------------------------------------------------------
// Softmax over the last dim (32): rows of 32 contiguous elements.
// ---------------------------------------------------------------------------
__global__ void softmax_kernel(const float* __restrict__ yp,
                               float* __restrict__ out)
{
    const int t  = threadIdx.x;
    const int r  = blockIdx.x * 8 + (t >> 5);  // 4096 rows
    const int od = t & 31;
    const float v = yp[(size_t)r * 32 + od];
    float m = v;
#pragma unroll
    for (int s = 16; s > 0; s >>= 1) m = fmaxf(m, __shfl_xor(m, s, 32));
    const float e = __expf(v - m);
    float sum = e;
#pragma unroll
    for (int s = 16; s > 0; s >>= 1) sum += __shfl_xor(sum, s, 32);
    out[(size_t)r * 32 + od] = e / sum;
}

// ---------------------------------------------------------------------------
extern "C" void kernel_launch(void* const* d_in, const int* in_sizes, int n_in,
                              void* d_out, int out_size, void* d_ws, size_t ws_size,
                              hipStream_t stream)
{
    const float* q    = (const float*)d_in[0];
    const float* k    = (const float*)d_in[1];
    const float* grid = (const float*)d_in[2];
    const float* bwq  = (const float*)d_in[3];
    const float* bwk  = (const float*)d_in[4];
    const float* cq   = (const float*)d_in[5];
    const float* ck   = (const float*)d_in[6];
    const float* cw   = (const float*)d_in[7];
    const float* cb   = (const float*)d_in[8];
    const float* ssp  = (const float*)d_in[9];
    float* out = (float*)d_out;

    short* Af   = (short*)d_ws;                                   // NS*2*64*8 shorts = 5242880 B
    float* ypre = (float*)((char*)d_ws + (size_t)NS * 2 * 64 * 16); // 131072*4 = 524288 B

    act_kernel<<<640, 256, 0, stream>>>(q, k, grid, cq, ck, Af);
    init_kernel<<<512, 256, 0, stream>>>(cb, ssp, ypre);
    gemm_kernel<<<2560, 256, 0, stream>>>(bwq, bwk, cw, Af, ssp, ypre);
    softmax_kernel<<<512, 256, 0, stream>>>(ypre, out);
}

// Round 5
// 160.875 us; speedup vs baseline: 6.7428x; 1.0501x over previous
//
#include <hip/hip_runtime.h>
#include <math.h>

#define N_TOT 4096   // H*P*D
#define PHO_T 4096   // P*H*OUT_DIM
#define KTOT  40960  // 2*N + 8*N
#define NS    2560   // total k16 steps = KTOT/16

typedef __attribute__((ext_vector_type(8)))  short short8v;  // 8 bf16 (4 VGPRs)
typedef __attribute__((ext_vector_type(16))) float f32x16;   // MFMA 32x32 acc

// global -> LDS direct DMA, 16 B per lane, dest = wave-uniform base + lane*16
#define GLD16(src, dst) __builtin_amdgcn_global_load_lds(                      \
    (const __attribute__((address_space(1))) void*)(src),                      \
    (__attribute__((address_space(3))) void*)(dst), 16, 0, 0)

// f32 -> (hi,lo) bf16, RNE on both (residual exact; dropped lo*lo term is
// zero-mean => no systematic bias in the GEMM)
__device__ __forceinline__ void split1(float x, short& h, short& l) {
    unsigned u  = __builtin_bit_cast(unsigned, x);
    unsigned hu = (u + 0x7FFFu + ((u >> 16) & 1u)) & 0xFFFF0000u;
    h = (short)(hu >> 16);
    float r = x - __builtin_bit_cast(float, hu);     // exact
    unsigned ur = __builtin_bit_cast(unsigned, r);
    l = (short)((ur + 0x7FFFu + ((ur >> 16) & 1u)) >> 16);
}

// ---------------------------------------------------------------------------
// Pass 1: A in MFMA-fragment order, hi/lo bf16 planes.
//   logical Act[k][b]: k<4096 silu(q), k<8192 silu(k), else sin-features.
//   fragment stream: for k16-step S, plane p, lane l:
//     Af[((S*2+p)*64 + l)*8 + j] = Act_p[b = l&31][k = S*16 + (l>>5)*8 + j]
//   (exactly the 32x32x16 bf16 A-operand layout; 1 KB per (S,p), coalesced)
// ---------------------------------------------------------------------------
__global__ void act_kernel(const float* __restrict__ q,
                           const float* __restrict__ kx,
                           const float* __restrict__ grid_,
                           const float* __restrict__ coefq,
                           const float* __restrict__ coefk,
                           short* __restrict__ Af)
{
    const int t = blockIdx.x * 256 + threadIdx.x;  // 163840 = NS * 64
    const int S = t >> 6;
    const int l = t & 63;
    const int b = l & 31;
    const int k0 = S * 16 + (l >> 5) * 8;          // 8-aligned; never crosses a region

    float v[8];
    if (k0 < 8192) {
        const float* src = (k0 < 4096) ? (q  + (size_t)b * N_TOT + k0)
                                       : (kx + (size_t)b * N_TOT + (k0 - 4096));
#pragma unroll
        for (int j = 0; j < 8; ++j) {
            const float x = src[j];
            v[j] = x / (1.f + __expf(-x));
        }
    } else {
        const int f  = (k0 - 8192) >> 12;
        const int n0 = (k0 - 8192) & 4095;         // 8-aligned -> same group for all j
        const int g  = n0 >> 6;
        const float gf  = grid_[f];
        const float cq_ = coefq[g * 8 + f];
        const float ck_ = coefk[g * 8 + f];
        const float* qp = q  + (size_t)b * N_TOT + n0;
        const float* kp = kx + (size_t)b * N_TOT + n0;
#pragma unroll
        for (int j = 0; j < 8; ++j)
            v[j] = sinf(gf * qp[j]) * cq_ + sinf(gf * kp[j]) * ck_;
    }

    short8v hi, lo;
#pragma unroll
    for (int j = 0; j < 8; ++j) { short h, lw; split1(v[j], h, lw); hi[j] = h; lo[j] = lw; }
    *(short8v*)&Af[((size_t)(S * 2 + 0) * 64 + l) * 8] = hi;
    *(short8v*)&Af[((size_t)(S * 2 + 1) * 64 + l) * 8] = lo;
}

// ---------------------------------------------------------------------------
// y_pre[b][o] initialized with the bias term: 2 * ss[o]^2 * sum_f conv_bq[f][o]
// ---------------------------------------------------------------------------
__global__ void init_kernel(const float* __restrict__ cb,
                            const float* __restrict__ ssp,
                            float* __restrict__ ypre)
{
    const int t = blockIdx.x * 256 + threadIdx.x;  // t = b*4096 + o
    const int o = t & 4095;
    const float s = ssp[o];
    float acc = 0.f;
#pragma unroll
    for (int f = 0; f < 8; ++f) acc += cb[f * PHO_T + o];
    ypre[t] = 2.f * s * s * acc;
}

// ---------------------------------------------------------------------------
// Main GEMM via split-bf16 MFMA: y[b][o] += sum_k Act[k][b] * W[k][o]
//   ~ ah*wh + ah*wl + al*wh  (3x mfma_f32_32x32x16_bf16)
// Grid: 32 K-supers (1280 k) x 16 o-blocks (256 o) = 512 blocks = 2/CU,
// ONE co-resident generation (no inter-generation HBM bubbles).
// Region (bwq/bwk/conv) resolved PER CHUNK (32-k chunks are region-pure:
// regions are 4096-aligned). Conv chunks accumulate into a separate acc pair
// (accS), scaled by ss[o]^2 in the epilogue: y += accU + ss^2*accS.
// W f32 staged by global_load_lds (XOR slot swizzle both sides, rule #21),
// converted to bf16 hi/lo in-register. A read as ready-made fragments.
// ---------------------------------------------------------------------------
#define OBK  256
#define KC   32
#define KSUP 1280
#define NCH  (KSUP / KC)   // 40 chunks per block

__global__ __launch_bounds__(256) void gemm_kernel(
    const float* __restrict__ bwq, const float* __restrict__ bwk,
    const float* __restrict__ cw,  const short* __restrict__ Af,
    const float* __restrict__ ssp, float* __restrict__ ypre)
{
    __shared__ float Wl[2][OBK * KC];   // 2 * 32 KB

    const int t  = threadIdx.x;
    const int ks = blockIdx.x >> 4;      // 0..31
    const int ob = blockIdx.x & 15;      // 0..15
    const int o_base = ob * OBK;
    const int k_base = ks * KSUP;

    const int w  = t >> 6;   // wave 0..3
    const int l  = t & 63;   // lane
    const int srow  = l >> 3;
    const int sslot = (l & 7) ^ (srow & 7);   // DMA source swizzle (rule #21)

    f32x16 accU0, accU1, accS0, accS1;
#pragma unroll
    for (int i = 0; i < 16; ++i) {
        accU0[i] = 0.f; accU1[i] = 0.f; accS0[i] = 0.f; accS1[i] = 0.f;
    }

    // weight row-pointer for global k index kg (chunk-uniform)
    auto wptr = [&](int kg) -> const float* {
        if (kg < 4096)  return bwq + kg;
        if (kg < 8192)  return bwk + (kg - 4096);
        const int f    = (kg - 8192) >> 12;
        const int noff = (kg - 8192) & 4095;
        return cw + (size_t)f * (size_t)PHO_T * N_TOT + noff;
    };

    // stage the 32-k chunk at global k kg into buffer buf (8 DMA instrs/wave)
    auto stage = [&](int kg, int buf) {
        const float* Wp = wptr(kg);
#pragma unroll
        for (int i = 0; i < 8; ++i) {
            const int row = w * 64 + i * 8 + srow;
            const float* src = Wp + (size_t)(o_base + row) * N_TOT + sslot * 4;
            GLD16(src, &Wl[buf][(w * 64 + i * 8) * KC]);
        }
    };

    stage(k_base, 0);
    __syncthreads();   // vmcnt(0) drain + barrier: chunk 0 resident

    const int rkey = l & 7;              // row&7 for both tiles (nt*32 = 0 mod 8)
    const int row0 = w * 64 + (l & 31);

    for (int c = 0; c < NCH; ++c) {
        const int cur = c & 1;
        const int kg  = k_base + c * KC;
        if (c + 1 < NCH) stage(kg + KC, cur ^ 1);   // DMA in flight over compute

        const bool sc = (kg >= 8192);    // conv region -> scaled accumulators
#pragma unroll
        for (int s = 0; s < 2; ++s) {
            const size_t Sg = (size_t)(kg >> 4) + s;
            const short8v ah = *(const short8v*)&Af[((Sg * 2 + 0) * 64 + l) * 8];
            const short8v al = *(const short8v*)&Af[((Sg * 2 + 1) * 64 + l) * 8];
            const int j0 = s * 4 + (l >> 5) * 2;   // logical f4 slot of this lane's 8 k

            auto tileop = [&](int nt, f32x16& acc) {
                const float* rp = &Wl[cur][(row0 + nt * 32) * KC];
                const float4 wa = *(const float4*)&rp[((j0    ) ^ rkey) * 4];
                const float4 wb = *(const float4*)&rp[((j0 + 1) ^ rkey) * 4];
                short8v bh, bl;
                {
                    short h, lw;
                    split1(wa.x, h, lw); bh[0] = h; bl[0] = lw;
                    split1(wa.y, h, lw); bh[1] = h; bl[1] = lw;
                    split1(wa.z, h, lw); bh[2] = h; bl[2] = lw;
                    split1(wa.w, h, lw); bh[3] = h; bl[3] = lw;
                    split1(wb.x, h, lw); bh[4] = h; bl[4] = lw;
                    split1(wb.y, h, lw); bh[5] = h; bl[5] = lw;
                    split1(wb.z, h, lw); bh[6] = h; bl[6] = lw;
                    split1(wb.w, h, lw); bh[7] = h; bl[7] = lw;
                }
                acc = __builtin_amdgcn_mfma_f32_32x32x16_bf16(ah, bh, acc, 0, 0, 0);
                acc = __builtin_amdgcn_mfma_f32_32x32x16_bf16(ah, bl, acc, 0, 0, 0);
                acc = __builtin_amdgcn_mfma_f32_32x32x16_bf16(al, bh, acc, 0, 0, 0);
            };
            if (sc) { tileop(0, accS0); tileop(1, accS1); }   // wave-uniform branch,
            else    { tileop(0, accU0); tileop(1, accU1); }   // static acc targets
        }
        // barrier: compiler-inserted vmcnt(0) drains next chunk's DMA; also
        // protects buffer `cur` from the following iteration's overwrite
        __syncthreads();
    }

    // epilogue: D layout (32x32): col = l&31, row(b) = (r&3) + 8*(r>>2) + 4*(l>>5)
    const int o0 = o_base + w * 64 + (l & 31);
    const int o1 = o0 + 32;
    const float x0 = ssp[o0], x1 = ssp[o1];
    const float s0 = x0 * x0, s1 = x1 * x1;
    const int bh4 = 4 * (l >> 5);
#pragma unroll
    for (int r = 0; r < 16; ++r) {
        const int b = (r & 3) + 8 * (r >> 2) + bh4;
        atomicAdd(&ypre[(size_t)b * PHO_T + o0], accU0[r] + accS0[r] * s0);
        atomicAdd(&ypre[(size_t)b * PHO_T + o1], accU1[r] + accS1[r] * s1);
    }
}

// ---------------------------------------------------------------------------
// Softmax over the last dim (32): rows of 32 contiguous elements.
// ---------------------------------------------------------------------------
__global__ void softmax_kernel(const float* __restrict__ yp,
                               float* __restrict__ out)
{
    const int t  = threadIdx.x;
    const int r  = blockIdx.x * 8 + (t >> 5);  // 4096 rows
    const int od = t & 31;
    const float v = yp[(size_t)r * 32 + od];
    float m = v;
#pragma unroll
    for (int s = 16; s > 0; s >>= 1) m = fmaxf(m, __shfl_xor(m, s, 32));
    const float e = __expf(v - m);
    float sum = e;
#pragma unroll
    for (int s = 16; s > 0; s >>= 1) sum += __shfl_xor(sum, s, 32);
    out[(size_t)r * 32 + od] = e / sum;
}

// ---------------------------------------------------------------------------
extern "C" void kernel_launch(void* const* d_in, const int* in_sizes, int n_in,
                              void* d_out, int out_size, void* d_ws, size_t ws_size,
                              hipStream_t stream)
{
    const float* q    = (const float*)d_in[0];
    const float* k    = (const float*)d_in[1];
    const float* grid = (const float*)d_in[2];
    const float* bwq  = (const float*)d_in[3];
    const float* bwk  = (const float*)d_in[4];
    const float* cq   = (const float*)d_in[5];
    const float* ck   = (const float*)d_in[6];
    const float* cw   = (const float*)d_in[7];
    const float* cb   = (const float*)d_in[8];
    const float* ssp  = (const float*)d_in[9];
    float* out = (float*)d_out;

    short* Af   = (short*)d_ws;                                   // NS*2*64*8 shorts = 5242880 B
    float* ypre = (float*)((char*)d_ws + (size_t)NS * 2 * 64 * 16); // 131072*4 = 524288 B

    act_kernel<<<640, 256, 0, stream>>>(q, k, grid, cq, ck, Af);
    init_kernel<<<512, 256, 0, stream>>>(cb, ssp, ypre);
    gemm_kernel<<<512, 256, 0, stream>>>(bwq, bwk, cw, Af, ssp, ypre);
    softmax_kernel<<<512, 256, 0, stream>>>(ypre, out);
}

// Round 6
// 142.617 us; speedup vs baseline: 7.6060x; 1.1280x over previous
//
#include <hip/hip_runtime.h>
#include <math.h>

#define N_TOT 4096   // H*P*D
#define PHO_T 4096   // P*H*OUT_DIM
#define KTOT  40960  // 2*N + 8*N
#define NS    2560   // total k16 steps = KTOT/16

typedef __attribute__((ext_vector_type(8)))  short short8v;  // 8 bf16 (4 VGPRs)
typedef __attribute__((ext_vector_type(16))) float f32x16;   // MFMA 32x32 acc

// global -> LDS direct DMA, 16 B per lane, dest = wave-uniform base + lane*16
#define GLD16(src, dst) __builtin_amdgcn_global_load_lds(                      \
    (const __attribute__((address_space(1))) void*)(src),                      \
    (__attribute__((address_space(3))) void*)(dst), 16, 0, 0)

// f32 -> (hi,lo) bf16, RNE on both (residual exact; dropped lo*lo term is
// zero-mean => no systematic bias in the GEMM)
__device__ __forceinline__ void split1(float x, short& h, short& l) {
    unsigned u  = __builtin_bit_cast(unsigned, x);
    unsigned hu = (u + 0x7FFFu + ((u >> 16) & 1u)) & 0xFFFF0000u;
    h = (short)(hu >> 16);
    float r = x - __builtin_bit_cast(float, hu);     // exact
    unsigned ur = __builtin_bit_cast(unsigned, r);
    l = (short)((ur + 0x7FFFu + ((ur >> 16) & 1u)) >> 16);
}

// ---------------------------------------------------------------------------
// Pass 1: A in MFMA-fragment order, hi/lo bf16 planes.
//   logical Act[k][b]: k<4096 silu(q), k<8192 silu(k), else sin-features.
//   fragment stream: for k16-step S, plane p, lane l:
//     Af[((S*2+p)*64 + l)*8 + j] = Act_p[b = l&31][k = S*16 + (l>>5)*8 + j]
//   (exactly the 32x32x16 bf16 A-operand layout; 1 KB per (S,p), coalesced)
// ---------------------------------------------------------------------------
__global__ void act_kernel(const float* __restrict__ q,
                           const float* __restrict__ kx,
                           const float* __restrict__ grid_,
                           const float* __restrict__ coefq,
                           const float* __restrict__ coefk,
                           short* __restrict__ Af)
{
    const int t = blockIdx.x * 256 + threadIdx.x;  // 163840 = NS * 64
    const int S = t >> 6;
    const int l = t & 63;
    const int b = l & 31;
    const int k0 = S * 16 + (l >> 5) * 8;          // 8-aligned; never crosses a region

    float v[8];
    if (k0 < 8192) {
        const float* src = (k0 < 4096) ? (q  + (size_t)b * N_TOT + k0)
                                       : (kx + (size_t)b * N_TOT + (k0 - 4096));
#pragma unroll
        for (int j = 0; j < 8; ++j) {
            const float x = src[j];
            v[j] = x / (1.f + __expf(-x));
        }
    } else {
        const int f  = (k0 - 8192) >> 12;
        const int n0 = (k0 - 8192) & 4095;         // 8-aligned -> same group for all j
        const int g  = n0 >> 6;
        const float gf  = grid_[f];
        const float cq_ = coefq[g * 8 + f];
        const float ck_ = coefk[g * 8 + f];
        const float* qp = q  + (size_t)b * N_TOT + n0;
        const float* kp = kx + (size_t)b * N_TOT + n0;
#pragma unroll
        for (int j = 0; j < 8; ++j)
            v[j] = __sinf(gf * qp[j]) * cq_ + __sinf(gf * kp[j]) * ck_;
    }

    short8v hi, lo;
#pragma unroll
    for (int j = 0; j < 8; ++j) { short h, lw; split1(v[j], h, lw); hi[j] = h; lo[j] = lw; }
    *(short8v*)&Af[((size_t)(S * 2 + 0) * 64 + l) * 8] = hi;
    *(short8v*)&Af[((size_t)(S * 2 + 1) * 64 + l) * 8] = lo;
}

// ---------------------------------------------------------------------------
// y_pre[b][o] initialized with the bias term: 2 * ss[o]^2 * sum_f conv_bq[f][o]
// ---------------------------------------------------------------------------
__global__ void init_kernel(const float* __restrict__ cb,
                            const float* __restrict__ ssp,
                            float* __restrict__ ypre)
{
    const int t = blockIdx.x * 256 + threadIdx.x;  // t = b*4096 + o
    const int o = t & 4095;
    const float s = ssp[o];
    float acc = 0.f;
#pragma unroll
    for (int f = 0; f < 8; ++f) acc += cb[f * PHO_T + o];
    ypre[t] = 2.f * s * s * acc;
}

// ---------------------------------------------------------------------------
// Main GEMM via split-bf16 MFMA: y[b][o] += sum_k Act[k][b] * W[k][o]
//   ~ ah*wh + ah*wl + al*wh  (3x mfma_f32_32x32x16_bf16)
// Grid: 32 K-supers (1280 k) x 16 o-blocks (256 o) = 512 blocks = 2/CU,
// one co-resident generation.
// BARRIER-FREE pipeline: each wave's MFMA tiles read ONLY the 64 LDS rows
// that wave DMAs itself (LDS is wave-private) -> no __syncthreads at all.
// Per-iteration issue order (vmcnt is one in-order counter!):
//   [4 Af loads (chunk c)] -> fence -> [8 DMA (chunk c+1)] -> vmcnt(8) -> compute
// vmcnt(8) retires chunk-c DMA + Af loads while keeping chunk-c+1's 8 DMAs
// in flight across the whole compute phase (T3/T4: never drain to 0 in-loop).
// Region (bwq/bwk/conv) resolved per chunk (region-pure, 4096-aligned);
// conv chunks use separate accumulators, scaled by ss^2 in the epilogue.
// W f32 staged with XOR slot swizzle on BOTH sides (rule #21), converted to
// bf16 hi/lo in-register. A read as ready-made fragments (L2/L3-resident).
// ---------------------------------------------------------------------------
#define OBK  256
#define KC   32
#define KSUP 1280
#define NCH  (KSUP / KC)   // 40 chunks per block

__global__ __launch_bounds__(256) void gemm_kernel(
    const float* __restrict__ bwq, const float* __restrict__ bwk,
    const float* __restrict__ cw,  const short* __restrict__ Af,
    const float* __restrict__ ssp, float* __restrict__ ypre)
{
    __shared__ float Wl[2][OBK * KC];   // 2 * 32 KB

    const int t  = threadIdx.x;
    const int ks = blockIdx.x >> 4;      // 0..31
    const int ob = blockIdx.x & 15;      // 0..15
    const int o_base = ob * OBK;
    const int k_base = ks * KSUP;

    const int w  = t >> 6;   // wave 0..3
    const int l  = t & 63;   // lane
    const int srow  = l >> 3;
    const int sslot = (l & 7) ^ (srow & 7);   // DMA source swizzle (rule #21)

    f32x16 accU0, accU1, accS0, accS1;
#pragma unroll
    for (int i = 0; i < 16; ++i) {
        accU0[i] = 0.f; accU1[i] = 0.f; accS0[i] = 0.f; accS1[i] = 0.f;
    }

    // weight row-pointer for global k index kg (chunk-uniform)
    auto wptr = [&](int kg) -> const float* {
        if (kg < 4096)  return bwq + kg;
        if (kg < 8192)  return bwk + (kg - 4096);
        const int f    = (kg - 8192) >> 12;
        const int noff = (kg - 8192) & 4095;
        return cw + (size_t)f * (size_t)PHO_T * N_TOT + noff;
    };

    // stage the 32-k chunk at global k kg into buffer buf (8 DMA instrs/wave;
    // wave w writes rows w*64 .. w*64+63 only)
    auto stage = [&](int kg, int buf) {
        const float* Wp = wptr(kg);
#pragma unroll
        for (int i = 0; i < 8; ++i) {
            const int row = w * 64 + i * 8 + srow;
            const float* src = Wp + (size_t)(o_base + row) * N_TOT + sslot * 4;
            GLD16(src, &Wl[buf][(w * 64 + i * 8) * KC]);
        }
    };

    const int rkey = l & 7;              // row&7 for both tiles (nt*32 = 0 mod 8)
    const int row0 = w * 64 + (l & 31);
    const int j0b  = (l >> 5) * 2;

    // compute chunk (kg, buffer cur) from LDS + prefetched A fragments
    auto compute = [&](int kg, int cur, const short8v& ah0, const short8v& al0,
                       const short8v& ah1, const short8v& al1) {
        const bool sc = (kg >= 8192);    // conv region -> scaled accumulators
#pragma unroll
        for (int s = 0; s < 2; ++s) {
            const short8v& ah = s ? ah1 : ah0;
            const short8v& al = s ? al1 : al0;
            const int j0 = s * 4 + j0b;

            auto tileop = [&](int nt, f32x16& acc) {
                const float* rp = &Wl[cur][(row0 + nt * 32) * KC];
                const float4 wa = *(const float4*)&rp[((j0    ) ^ rkey) * 4];
                const float4 wb = *(const float4*)&rp[((j0 + 1) ^ rkey) * 4];
                short8v bh, bl;
                {
                    short h, lw;
                    split1(wa.x, h, lw); bh[0] = h; bl[0] = lw;
                    split1(wa.y, h, lw); bh[1] = h; bl[1] = lw;
                    split1(wa.z, h, lw); bh[2] = h; bl[2] = lw;
                    split1(wa.w, h, lw); bh[3] = h; bl[3] = lw;
                    split1(wb.x, h, lw); bh[4] = h; bl[4] = lw;
                    split1(wb.y, h, lw); bh[5] = h; bl[5] = lw;
                    split1(wb.z, h, lw); bh[6] = h; bl[6] = lw;
                    split1(wb.w, h, lw); bh[7] = h; bl[7] = lw;
                }
                acc = __builtin_amdgcn_mfma_f32_32x32x16_bf16(ah, bh, acc, 0, 0, 0);
                acc = __builtin_amdgcn_mfma_f32_32x32x16_bf16(ah, bl, acc, 0, 0, 0);
                acc = __builtin_amdgcn_mfma_f32_32x32x16_bf16(al, bh, acc, 0, 0, 0);
            };
            if (sc) { tileop(0, accS0); tileop(1, accS1); }   // wave-uniform branch,
            else    { tileop(0, accU0); tileop(1, accU1); }   // static acc targets
        }
    };

    // prologue: chunk 0 DMA in flight
    stage(k_base, 0);

    short8v ah0, al0, ah1, al1;
    for (int c = 0; c < NCH - 1; ++c) {
        const int cur = c & 1;
        const int kg  = k_base + c * KC;
        const size_t Sg = (size_t)(kg >> 4);
        // A fragments for chunk c (issued BEFORE next chunk's DMA)
        ah0 = *(const short8v*)&Af[(((Sg    ) * 2 + 0) * 64 + l) * 8];
        al0 = *(const short8v*)&Af[(((Sg    ) * 2 + 1) * 64 + l) * 8];
        ah1 = *(const short8v*)&Af[(((Sg + 1) * 2 + 0) * 64 + l) * 8];
        al1 = *(const short8v*)&Af[(((Sg + 1) * 2 + 1) * 64 + l) * 8];
        asm volatile("" ::: "memory");            // pin Af loads above the DMAs
        stage(kg + KC, cur ^ 1);                  // chunk c+1 DMA, stays in flight
        asm volatile("s_waitcnt vmcnt(8)" ::: "memory");  // chunk c + Af landed
        __builtin_amdgcn_sched_barrier(0);
        compute(kg, cur, ah0, al0, ah1, al1);
    }
    {   // peeled last chunk: drain everything
        const int c   = NCH - 1;
        const int kg  = k_base + c * KC;
        const size_t Sg = (size_t)(kg >> 4);
        ah0 = *(const short8v*)&Af[(((Sg    ) * 2 + 0) * 64 + l) * 8];
        al0 = *(const short8v*)&Af[(((Sg    ) * 2 + 1) * 64 + l) * 8];
        ah1 = *(const short8v*)&Af[(((Sg + 1) * 2 + 0) * 64 + l) * 8];
        al1 = *(const short8v*)&Af[(((Sg + 1) * 2 + 1) * 64 + l) * 8];
        asm volatile("s_waitcnt vmcnt(0)" ::: "memory");
        __builtin_amdgcn_sched_barrier(0);
        compute(kg, c & 1, ah0, al0, ah1, al1);
    }

    // epilogue: D layout (32x32): col = l&31, row(b) = (r&3) + 8*(r>>2) + 4*(l>>5)
    const int o0 = o_base + w * 64 + (l & 31);
    const int o1 = o0 + 32;
    const float x0 = ssp[o0], x1 = ssp[o1];
    const float s0 = x0 * x0, s1 = x1 * x1;
    const int bh4 = 4 * (l >> 5);
#pragma unroll
    for (int r = 0; r < 16; ++r) {
        const int b = (r & 3) + 8 * (r >> 2) + bh4;
        atomicAdd(&ypre[(size_t)b * PHO_T + o0], accU0[r] + accS0[r] * s0);
        atomicAdd(&ypre[(size_t)b * PHO_T + o1], accU1[r] + accS1[r] * s1);
    }
}

// ---------------------------------------------------------------------------
// Softmax over the last dim (32): rows of 32 contiguous elements.
// ---------------------------------------------------------------------------
__global__ void softmax_kernel(const float* __restrict__ yp,
                               float* __restrict__ out)
{
    const int t  = threadIdx.x;
    const int r  = blockIdx.x * 8 + (t >> 5);  // 4096 rows
    const int od = t & 31;
    const float v = yp[(size_t)r * 32 + od];
    float m = v;
#pragma unroll
    for (int s = 16; s > 0; s >>= 1) m = fmaxf(m, __shfl_xor(m, s, 32));
    const float e = __expf(v - m);
    float sum = e;
#pragma unroll
    for (int s = 16; s > 0; s >>= 1) sum += __shfl_xor(sum, s, 32);
    out[(size_t)r * 32 + od] = e / sum;
}

// ---------------------------------------------------------------------------
extern "C" void kernel_launch(void* const* d_in, const int* in_sizes, int n_in,
                              void* d_out, int out_size, void* d_ws, size_t ws_size,
                              hipStream_t stream)
{
    const float* q    = (const float*)d_in[0];
    const float* k    = (const float*)d_in[1];
    const float* grid = (const float*)d_in[2];
    const float* bwq  = (const float*)d_in[3];
    const float* bwk  = (const float*)d_in[4];
    const float* cq   = (const float*)d_in[5];
    const float* ck   = (const float*)d_in[6];
    const float* cw   = (const float*)d_in[7];
    const float* cb   = (const float*)d_in[8];
    const float* ssp  = (const float*)d_in[9];
    float* out = (float*)d_out;

    short* Af   = (short*)d_ws;                                   // NS*2*64*8 shorts = 5242880 B
    float* ypre = (float*)((char*)d_ws + (size_t)NS * 2 * 64 * 16); // 131072*4 = 524288 B

    act_kernel<<<640, 256, 0, stream>>>(q, k, grid, cq, ck, Af);
    init_kernel<<<512, 256, 0, stream>>>(cb, ssp, ypre);
    gemm_kernel<<<512, 256, 0, stream>>>(bwq, bwk, cw, Af, ssp, ypre);
    softmax_kernel<<<512, 256, 0, stream>>>(ypre, out);
}